// Round 4
// baseline (246.092 us; speedup 1.0000x reference)
//
#include <hip/hip_runtime.h>
#include <math.h>

#define T_DIM 4096
#define B_DIM 8
#define C_DIM 1024
#define H_DIM 16
#define K_DIM 31
#define PAD_L 30
#define TILE_T 32
#define WIN 62                 // TILE_T + K_DIM - 1
#define BLOCK 64               // ONE wave per block: all sync is wave-local
#define COLS 64                // columns owned by the wave
#define RING 64                // LDS row ring (mod-64)
#define TPB 8                  // t-tiles per block

typedef __attribute__((ext_vector_type(4))) float f32x4;

// Async global->LDS DMA, 16 B/lane. Lane l -> LDS bytes [l*16, l*16+16).
// With a [4][64] f32 tile that is row r = l>>4, cols (l&15)*4.. +3: one
// instr stages FOUR consecutive t-rows of this wave's 64 columns.
__device__ __forceinline__ void stage16(const float* g, float* l) {
    __builtin_amdgcn_global_load_lds(
        (const __attribute__((address_space(1))) void*)g,
        (__attribute__((address_space(3))) void*)l,
        16, 0, 0);
}

// Window row J of the tile at t0 lives in ring slot (t0 + J - 30) & 63.
// TPAR = t0 & 63 (0 or 32) => every LDS offset / acc index / taps index is a
// compile-time constant (R4 lesson: runtime-indexed private arrays -> scratch;
// constant LDS offsets also let alias analysis prove stage/read disjointness).
template <int TPAR, int J>
__device__ __forceinline__ void conv_a(const float* col,
                                       const float (&taps)[K_DIM],
                                       float (&acc)[TILE_T]) {
    if constexpr (J < 30) {
        const float xj = col[((TPAR + J + 34) & 63) * COLS];
        #pragma unroll
        for (int i = 0; i <= J; ++i) {
            if (i == J) acc[i] = taps[0] * xj;      // init: no zero pass
            else        acc[i] = fmaf(taps[J - i], xj, acc[i]);
        }
        conv_a<TPAR, J + 1>(col, taps, acc);
    }
}

template <int TPAR, int J>
__device__ __forceinline__ void conv_b(const float* col,
                                       const float (&taps)[K_DIM],
                                       float (&acc)[TILE_T],
                                       float* po, long stride) {
    if constexpr (J < WIN) {
        const float xj = col[((TPAR + J + 34) & 63) * COLS];
        constexpr int ilo = J - 30;
        constexpr int ihi = (J < TILE_T - 1) ? J : TILE_T - 1;
        #pragma unroll
        for (int i = ilo; i <= ihi; ++i) {
            if (i == J) acc[i] = taps[0] * xj;
            else        acc[i] = fmaf(taps[J - i], xj, acc[i]);
        }
        // acc[J-30] complete: stream it out (nontemporal: keep x in L3)
        __builtin_nontemporal_store(acc[J - 30], po + (long)(J - 30) * stride);
        conv_b<TPAR, J + 1>(col, taps, acc, po, stride);
    }
}

// One tile, barrier-free:
//   conv_a reads the 30 oldest rows (slots about to be recycled)
//   counted wait: stage(k-1)'s 8 loads retired (allowance 32 = last iter's
//     stores stay in flight; vmcnt NEVER drains to 0 in the loop) + lgkm(0)
//     (conv_a's ds_reads done before their slots are overwritten)
//   issue stage(k): rows t0+32..t0+63 into the slots conv_a vacated
//   conv_b computes on rows staged LAST iteration while the DMA flies
template <int TPAR>
__device__ __forceinline__ void iter_body(
    const float* __restrict__ x, float* __restrict__ out,
    const float* col, float* lds0, const float (&taps)[K_DIM],
    long t0, int c0, int lane, int lrow, int lcol, bool stage_next)
{
    const long stride = (long)B_DIM * C_DIM;
    float acc[TILE_T];

    conv_a<TPAR, 0>(col, taps, acc);

    asm volatile("s_waitcnt vmcnt(32) lgkmcnt(0)" ::: "memory");

    if (stage_next) {                  // rows t0+32 .. t0+63, 4 rows/instr
        const float* gp = x + (t0 + TILE_T + lrow) * stride + c0 + lcol;
        #pragma unroll
        for (int g = 0; g < 8; ++g) {
            const int slot = (TPAR + TILE_T + 4 * g) & 63;   // compile-time
            stage16(gp + (long)(4 * g) * stride, lds0 + slot * COLS);
        }
    }

    float* po = out + t0 * stride + c0 + lane;
    conv_b<TPAR, 30>(col, taps, acc, po, stride);
}

__global__ __launch_bounds__(BLOCK, 2) void lightconv_kernel(
    const float* __restrict__ x,
    const float* __restrict__ w,
    float* __restrict__ out)
{
    __shared__ float ring[RING][COLS];          // 16 KiB -> 10 blocks/CU cap

    const int lane   = threadIdx.x;             // one wave
    const int colBlk = blockIdx.x;              // 0..127 (B*C / 64)
    const int tg     = blockIdx.y;              // 0..15  (T / (TPB*32))
    const int c0     = colBlk * COLS;
    const long stride = (long)B_DIM * C_DIM;
    const long tgbase = (long)tg * (TPB * TILE_T);   // ≡ 0 mod 64

    const int lrow = lane >> 4;                 // staging lane decomposition
    const int lcol = (lane & 15) << 2;

    // ---- prologue: stage rows tgbase-32 .. tgbase+31 into slots 32..63,0..31
    {
        const float* gp = x + (tgbase - 32 + lrow) * stride + c0 + lcol;
        if (tg > 0) {
            #pragma unroll
            for (int g = 0; g < 16; ++g) {
                const int slot = (32 + 4 * g) & 63;
                stage16(gp + (long)(4 * g) * stride, &ring[slot][0]);
            }
        } else {                                // rows < 0: zeros (slots 32..63)
            #pragma unroll
            for (int g = 0; g < 8; ++g) {
                const int slot = 32 + 4 * g;
                *(f32x4*)(&ring[slot][0] + lane * 4) = (f32x4){0.f, 0.f, 0.f, 0.f};
            }
            #pragma unroll
            for (int g = 8; g < 16; ++g) {
                const int slot = (32 + 4 * g) & 63;
                stage16(gp + (long)(4 * g) * stride, &ring[slot][0]);
            }
        }
    }

    // ---- redundant per-wave softmax -> SGPR taps (overlaps staging DMA) ----
    float taps[K_DIM];
    {
        const float* wr = w + (colBlk & 15) * K_DIM;    // head = (c0%1024)/64
        float tv[K_DIM];
        float m = -1e30f;
        #pragma unroll
        for (int k = 0; k < K_DIM; ++k) { tv[k] = wr[k]; m = fmaxf(m, tv[k]); }
        float s = 0.f;
        #pragma unroll
        for (int k = 0; k < K_DIM; ++k) { tv[k] = __expf(tv[k] - m); s += tv[k]; }
        const float inv = 1.0f / s;
        #pragma unroll
        for (int k = 0; k < K_DIM; ++k)
            taps[k] = __int_as_float(__builtin_amdgcn_readfirstlane(
                          __float_as_int(tv[k] * inv)));
    }

    // prologue drain: wave-local, the only vmcnt(0) in the kernel
    asm volatile("s_waitcnt vmcnt(0)" ::: "memory");

    const float* col = &ring[0][0] + lane;
    float* lds0 = &ring[0][0];
    long t0 = tgbase;
    #pragma unroll 1
    for (int k = 0; k < TPB; ++k, t0 += TILE_T) {
        const bool sn = (k < TPB - 1);
        if (k & 1) iter_body<32>(x, out, col, lds0, taps, t0, c0, lane, lrow, lcol, sn);
        else       iter_body< 0>(x, out, col, lds0, taps, t0, c0, lane, lrow, lcol, sn);
    }
}

extern "C" void kernel_launch(void* const* d_in, const int* in_sizes, int n_in,
                              void* d_out, int out_size, void* d_ws, size_t ws_size,
                              hipStream_t stream) {
    const float* x = (const float*)d_in[0];    // [T, B, C] fp32
    const float* w = (const float*)d_in[1];    // [H, K]    fp32
    float* out = (float*)d_out;                // [T, B, C] fp32

    dim3 grid((B_DIM * C_DIM) / COLS, T_DIM / (TPB * TILE_T));  // (128, 16)
    lightconv_kernel<<<grid, BLOCK, 0, stream>>>(x, w, out);
}

// Round 5
// 231.423 us; speedup vs baseline: 1.0634x; 1.0634x over previous
//
#include <hip/hip_runtime.h>
#include <math.h>

#define T_DIM 4096
#define B_DIM 8
#define C_DIM 1024
#define H_DIM 16
#define K_DIM 31
#define PAD_L 30
#define HALO 30                // K_DIM - 1
#define TILE_T 16              // outputs per thread
#define WROWS (TILE_T + HALO)  // 46 staged rows
#define BLOCK 256
#define CC 256                 // columns per block (1 KB contiguous per row)

typedef __attribute__((ext_vector_type(4))) float f32x4;

// Async global->LDS DMA: 64 lanes x 16 B = one full 1 KB row (256 floats).
__device__ __forceinline__ void stage16(const float* g, float* l) {
    __builtin_amdgcn_global_load_lds(
        (const __attribute__((address_space(1))) void*)g,
        (__attribute__((address_space(3))) void*)l,
        16, 0, 0);
}

// Window row J (t = t0 - 30 + J) feeds outputs i in [max(0,J-30), min(15,J)]
// with tap k = J - i. Template recursion: every acc/taps/LDS index is a
// compile-time constant (R4 lesson: runtime-indexed private arrays -> scratch).
// acc[i] initialized at J == i via taps[0]*x (no zero pass); acc[J-30] is
// complete at row J and streamed out immediately (shortens acc live ranges).
template <int J>
__device__ __forceinline__ void conv_all(const float* col,
                                         const float (&taps)[K_DIM],
                                         float (&acc)[TILE_T],
                                         float* po, long stride) {
    if constexpr (J < WROWS) {
        const float xj = col[J * CC];
        constexpr int ilo = (J > HALO) ? (J - HALO) : 0;
        constexpr int ihi = (J < TILE_T - 1) ? J : TILE_T - 1;
        #pragma unroll
        for (int i = ilo; i <= ihi; ++i) {
            if (i == J) acc[i] = taps[0] * xj;
            else        acc[i] = fmaf(taps[J - i], xj, acc[i]);
        }
        if constexpr (J >= HALO)
            __builtin_nontemporal_store(acc[J - HALO],
                                        po + (long)(J - HALO) * stride);
        conv_all<J + 1>(col, taps, acc, po, stride);
    }
}

// R8: same two-phase shape as the 79us R5 kernel (stage-all -> sync ->
// compute -> store; 1 KB contiguous global_load_lds per row) but TILE_T
// halved: LDS 62 KB -> 46 KB => 3 blocks/CU instead of 2 (12 waves/CU),
// three phase-offset fetch streams per CU with 2x shorter phase period.
// Extra window re-reads (2.875x vs 1.94x) are L3 hits: x is LLC-resident
// (FETCH_SIZE < compulsory in every round measured).
__global__ __launch_bounds__(BLOCK, 3) void lightconv_kernel(
    const float* __restrict__ x,
    const float* __restrict__ w,
    float* __restrict__ out)
{
    __shared__ float tile[WROWS][CC];   // 47104 B -> 3 blocks/CU

    const int tid    = threadIdx.x;
    const int lane   = tid & 63;
    const int wv     = tid >> 6;
    const int colBlk = blockIdx.x;      // 0..31  (B*C / CC)
    const int tBlk   = blockIdx.y;      // 0..255 (T / TILE_T)
    const int t0     = tBlk * TILE_T;
    const int cc0    = colBlk * CC;
    const long stride = (long)B_DIM * C_DIM;   // 8192

    // ---- stage rows t0-30 .. t0+15; wave wv owns rows wv*12 .. (+11|+9) ----
    {
        const int r0 = wv * 12;
        const int rn = (wv == 3) ? WROWS - 36 : 12;   // wave 3: 10 rows
        const float* gbase = x + (long)(t0 - HALO) * stride + cc0 + lane * 4;
        #pragma unroll
        for (int i = 0; i < 12; ++i) {
            if (i < rn) {                              // wave-uniform
                const int r = r0 + i;
                if (t0 - HALO + r >= 0) {              // uniform; only tBlk==0 pads
                    stage16(gbase + (long)r * stride, &tile[r][0]);
                } else {
                    *(f32x4*)&tile[r][lane * 4] = (f32x4){0.f, 0.f, 0.f, 0.f};
                }
            }
        }
    }

    // ---- redundant per-wave softmax -> SGPR taps (overlaps staging DMA) ----
    // wave wv spans head h = (cc0 % C)/64 + wv; all lanes compute identical
    // values from broadcast loads; readfirstlane pins to SGPRs.
    float taps[K_DIM];
    {
        const float* wr = w + (((colBlk & 3) << 2) + wv) * K_DIM;
        float tv[K_DIM];
        float m = -1e30f;
        #pragma unroll
        for (int k = 0; k < K_DIM; ++k) { tv[k] = wr[k]; m = fmaxf(m, tv[k]); }
        float s = 0.f;
        #pragma unroll
        for (int k = 0; k < K_DIM; ++k) { tv[k] = __expf(tv[k] - m); s += tv[k]; }
        const float inv = 1.0f / s;
        #pragma unroll
        for (int k = 0; k < K_DIM; ++k)
            taps[k] = __int_as_float(__builtin_amdgcn_readfirstlane(
                          __float_as_int(tv[k] * inv)));
    }

    __syncthreads();   // drains staging vmcnt; tile ready

    // ---- 46 LDS rows through 16 accumulators, stores interleaved ----
    float acc[TILE_T];
    float* po = out + (long)t0 * stride + cc0 + tid;
    conv_all<0>(&tile[0][0] + tid, taps, acc, po, stride);
}

extern "C" void kernel_launch(void* const* d_in, const int* in_sizes, int n_in,
                              void* d_out, int out_size, void* d_ws, size_t ws_size,
                              hipStream_t stream) {
    const float* x = (const float*)d_in[0];    // [T, B, C] fp32
    const float* w = (const float*)d_in[1];    // [H, K]    fp32
    float* out = (float*)d_out;                // [T, B, C] fp32

    dim3 grid((B_DIM * C_DIM) / CC, T_DIM / TILE_T);   // (32, 256)
    lightconv_kernel<<<grid, BLOCK, 0, stream>>>(x, w, out);
}

// Round 6
// 230.778 us; speedup vs baseline: 1.0664x; 1.0028x over previous
//
#include <hip/hip_runtime.h>
#include <math.h>

#define T_DIM 4096
#define B_DIM 8
#define C_DIM 1024
#define H_DIM 16
#define K_DIM 31
#define PAD_L 30
#define HALO 30                // K_DIM - 1
#define TILE_T 16              // outputs per thread
#define WROWS (TILE_T + HALO)  // 46 staged rows
#define BLOCK 256
#define CC 256                 // columns per block (1 KB contiguous per row)

typedef __attribute__((ext_vector_type(4))) float f32x4;

// Async global->LDS DMA: 64 lanes x 16 B = one full 1 KB row (256 floats).
__device__ __forceinline__ void stage16(const float* g, float* l) {
    __builtin_amdgcn_global_load_lds(
        (const __attribute__((address_space(1))) void*)g,
        (__attribute__((address_space(3))) void*)l,
        16, 0, 0);
}

// Window row J (t = t0 - 30 + J) feeds outputs i in [max(0,J-30), min(15,J)]
// with tap k = J - i. Template recursion: every acc/taps/LDS index is a
// compile-time constant (R4 lesson: runtime-indexed private arrays -> scratch).
// acc[i] initialized at J == i via taps[0]*x (no zero pass); acc[J-30] is
// complete at row J and streamed out immediately (shortens acc live ranges).
//
// R9 single-variable change vs R8: PLAIN cached stores instead of
// __builtin_nontemporal_store. Theory: nt streamed 131 MB of output to HBM
// during the kernel, fine-interleaved with read misses (R/W turnaround =
// the invariant 2.6 TB/s wall across R5-R8). Plain stores are full-line
// (256 B/wave contiguous, no RFO) and let L2/LLC absorb the output; the
// 537 MB poison-fill that follows pays the eviction outside our dispatch.
template <int J>
__device__ __forceinline__ void conv_all(const float* col,
                                         const float (&taps)[K_DIM],
                                         float (&acc)[TILE_T],
                                         float* po, long stride) {
    if constexpr (J < WROWS) {
        const float xj = col[J * CC];
        constexpr int ilo = (J > HALO) ? (J - HALO) : 0;
        constexpr int ihi = (J < TILE_T - 1) ? J : TILE_T - 1;
        #pragma unroll
        for (int i = ilo; i <= ihi; ++i) {
            if (i == J) acc[i] = taps[0] * xj;
            else        acc[i] = fmaf(taps[J - i], xj, acc[i]);
        }
        if constexpr (J >= HALO)
            po[(long)(J - HALO) * stride] = acc[J - HALO];   // cached store
        conv_all<J + 1>(col, taps, acc, po, stride);
    }
}

__global__ __launch_bounds__(BLOCK, 3) void lightconv_kernel(
    const float* __restrict__ x,
    const float* __restrict__ w,
    float* __restrict__ out)
{
    __shared__ float tile[WROWS][CC];   // 47104 B -> 3 blocks/CU

    const int tid    = threadIdx.x;
    const int lane   = tid & 63;
    const int wv     = tid >> 6;
    const int colBlk = blockIdx.x;      // 0..31  (B*C / CC)
    const int tBlk   = blockIdx.y;      // 0..255 (T / TILE_T)
    const int t0     = tBlk * TILE_T;
    const int cc0    = colBlk * CC;
    const long stride = (long)B_DIM * C_DIM;   // 8192

    // ---- stage rows t0-30 .. t0+15; wave wv owns rows wv*12 .. (+11|+9) ----
    {
        const int r0 = wv * 12;
        const int rn = (wv == 3) ? WROWS - 36 : 12;   // wave 3: 10 rows
        const float* gbase = x + (long)(t0 - HALO) * stride + cc0 + lane * 4;
        #pragma unroll
        for (int i = 0; i < 12; ++i) {
            if (i < rn) {                              // wave-uniform
                const int r = r0 + i;
                if (t0 - HALO + r >= 0) {              // uniform; only tBlk==0 pads
                    stage16(gbase + (long)r * stride, &tile[r][0]);
                } else {
                    *(f32x4*)&tile[r][lane * 4] = (f32x4){0.f, 0.f, 0.f, 0.f};
                }
            }
        }
    }

    // ---- redundant per-wave softmax -> SGPR taps (overlaps staging DMA) ----
    // wave wv spans head h = (cc0 % C)/64 + wv; all lanes compute identical
    // values from broadcast loads; readfirstlane pins to SGPRs.
    float taps[K_DIM];
    {
        const float* wr = w + (((colBlk & 3) << 2) + wv) * K_DIM;
        float tv[K_DIM];
        float m = -1e30f;
        #pragma unroll
        for (int k = 0; k < K_DIM; ++k) { tv[k] = wr[k]; m = fmaxf(m, tv[k]); }
        float s = 0.f;
        #pragma unroll
        for (int k = 0; k < K_DIM; ++k) { tv[k] = __expf(tv[k] - m); s += tv[k]; }
        const float inv = 1.0f / s;
        #pragma unroll
        for (int k = 0; k < K_DIM; ++k)
            taps[k] = __int_as_float(__builtin_amdgcn_readfirstlane(
                          __float_as_int(tv[k] * inv)));
    }

    __syncthreads();   // drains staging vmcnt; tile ready

    // ---- 46 LDS rows through 16 accumulators, stores interleaved ----
    float acc[TILE_T];
    float* po = out + (long)t0 * stride + cc0 + tid;
    conv_all<0>(&tile[0][0] + tid, taps, acc, po, stride);
}

extern "C" void kernel_launch(void* const* d_in, const int* in_sizes, int n_in,
                              void* d_out, int out_size, void* d_ws, size_t ws_size,
                              hipStream_t stream) {
    const float* x = (const float*)d_in[0];    // [T, B, C] fp32
    const float* w = (const float*)d_in[1];    // [H, K]    fp32
    float* out = (float*)d_out;                // [T, B, C] fp32

    dim3 grid((B_DIM * C_DIM) / CC, T_DIM / TILE_T);   // (32, 256)
    lightconv_kernel<<<grid, BLOCK, 0, stream>>>(x, w, out);
}

// Round 7
// 228.054 us; speedup vs baseline: 1.0791x; 1.0119x over previous
//
#include <hip/hip_runtime.h>
#include <math.h>

#define T_DIM 4096
#define B_DIM 8
#define C_DIM 1024
#define H_DIM 16
#define K_DIM 31
#define PAD_L 30
#define HALO 30                // K_DIM - 1
#define TILE_T 16              // outputs per thread
#define WROWS (TILE_T + HALO)  // 46 staged rows
#define BLOCK 256
#define CC 256                 // columns per block (1 KB contiguous per row)

typedef __attribute__((ext_vector_type(4))) float f32x4;

// Async global->LDS DMA: 64 lanes x 16 B = one full 1 KB row (256 floats).
__device__ __forceinline__ void stage16(const float* g, float* l) {
    __builtin_amdgcn_global_load_lds(
        (const __attribute__((address_space(1))) void*)g,
        (__attribute__((address_space(3))) void*)l,
        16, 0, 0);
}

// Window row J (t = t0 - 30 + J) feeds outputs i in [max(0,J-30), min(15,J)]
// with tap k = J - i. Template recursion: every acc/taps/LDS index is a
// compile-time constant (R4 lesson: runtime-indexed private arrays -> scratch).
template <int J>
__device__ __forceinline__ void conv_all(const float* col,
                                         const float (&taps)[K_DIM],
                                         float (&acc)[TILE_T],
                                         float* po, long stride) {
    if constexpr (J < WROWS) {
        const float xj = col[J * CC];
        constexpr int ilo = (J > HALO) ? (J - HALO) : 0;
        constexpr int ihi = (J < TILE_T - 1) ? J : TILE_T - 1;
        #pragma unroll
        for (int i = ilo; i <= ihi; ++i) {
            if (i == J) acc[i] = taps[0] * xj;
            else        acc[i] = fmaf(taps[J - i], xj, acc[i]);
        }
        if constexpr (J >= HALO)
            po[(long)(J - HALO) * stride] = acc[J - HALO];   // cached store
        conv_all<J + 1>(col, taps, acc, po, stride);
    }
}

// R10 single-variable change vs R9 (78.9us): break whole-GPU PHASE-LOCK.
// Theory: every block alternates [stage burst + vmcnt drain] (memory-only)
// with [compute] (memory-idle). All resident blocks start at t=0, have equal
// durations, and relaunch on completion -> the 3 slots/CU breathe in unison
// forever; memory duty cycle = 201MB / 6.3TB/s / 79us = 40% = the invariant
// wall across R5-R9. Fix: stagger the INITIAL resident set (flat id < 768;
// x-major dispatch puts a CU's initial slots at ids {i, i+256, i+512}) by
// ~2.5us per slot. Completion-driven relaunch self-sustains the offset.
__global__ __launch_bounds__(BLOCK, 3) void lightconv_kernel(
    const float* __restrict__ x,
    const float* __restrict__ w,
    float* __restrict__ out)
{
    __shared__ float tile[WROWS][CC];   // 47104 B -> 3 blocks/CU

    const int tid    = threadIdx.x;
    const int lane   = tid & 63;
    const int wv     = tid >> 6;
    const int colBlk = blockIdx.x;      // 0..31  (B*C / CC)
    const int tBlk   = blockIdx.y;      // 0..255 (T / TILE_T)
    const int t0     = tBlk * TILE_T;
    const int cc0    = colBlk * CC;
    const long stride = (long)B_DIM * C_DIM;   // 8192

    // ---- phase-stagger the initial resident wave of blocks ----
    {
        const int flat = blockIdx.y * gridDim.x + blockIdx.x;
        if (flat < 3 * 256) {
            const int slot = flat >> 8;            // 0, 1, 2
            for (int s = 0; s < slot * 6; ++s)
                __builtin_amdgcn_s_sleep(16);      // ~1024 cy each; ~2.6us/slot
        }
    }

    // ---- stage rows t0-30 .. t0+15; wave wv owns rows wv*12 .. (+11|+9) ----
    {
        const int r0 = wv * 12;
        const int rn = (wv == 3) ? WROWS - 36 : 12;   // wave 3: 10 rows
        const float* gbase = x + (long)(t0 - HALO) * stride + cc0 + lane * 4;
        #pragma unroll
        for (int i = 0; i < 12; ++i) {
            if (i < rn) {                              // wave-uniform
                const int r = r0 + i;
                if (t0 - HALO + r >= 0) {              // uniform; only tBlk==0 pads
                    stage16(gbase + (long)r * stride, &tile[r][0]);
                } else {
                    *(f32x4*)&tile[r][lane * 4] = (f32x4){0.f, 0.f, 0.f, 0.f};
                }
            }
        }
    }

    // ---- redundant per-wave softmax -> SGPR taps (overlaps staging DMA) ----
    float taps[K_DIM];
    {
        const float* wr = w + (((colBlk & 3) << 2) + wv) * K_DIM;
        float tv[K_DIM];
        float m = -1e30f;
        #pragma unroll
        for (int k = 0; k < K_DIM; ++k) { tv[k] = wr[k]; m = fmaxf(m, tv[k]); }
        float s = 0.f;
        #pragma unroll
        for (int k = 0; k < K_DIM; ++k) { tv[k] = __expf(tv[k] - m); s += tv[k]; }
        const float inv = 1.0f / s;
        #pragma unroll
        for (int k = 0; k < K_DIM; ++k)
            taps[k] = __int_as_float(__builtin_amdgcn_readfirstlane(
                          __float_as_int(tv[k] * inv)));
    }

    __syncthreads();   // drains staging vmcnt; tile ready

    // ---- 46 LDS rows through 16 accumulators, stores interleaved ----
    float acc[TILE_T];
    float* po = out + (long)t0 * stride + cc0 + tid;
    conv_all<0>(&tile[0][0] + tid, taps, acc, po, stride);
}

extern "C" void kernel_launch(void* const* d_in, const int* in_sizes, int n_in,
                              void* d_out, int out_size, void* d_ws, size_t ws_size,
                              hipStream_t stream) {
    const float* x = (const float*)d_in[0];    // [T, B, C] fp32
    const float* w = (const float*)d_in[1];    // [H, K]    fp32
    float* out = (float*)d_out;                // [T, B, C] fp32

    dim3 grid((B_DIM * C_DIM) / CC, T_DIM / TILE_T);   // (32, 256)
    lightconv_kernel<<<grid, BLOCK, 0, stream>>>(x, w, out);
}